// Round 8
// baseline (334.568 us; speedup 1.0000x reference)
//
#include <hip/hip_runtime.h>
#include <hip/hip_bf16.h>
#include <stdint.h>

#define BB 2
#define SS 2048
#define DD 1024
#define HH 16
#define HDIM 64
#define MM (BB*SS)   // 4096

typedef __attribute__((ext_vector_type(4))) float f32x4;
typedef __attribute__((ext_vector_type(16))) float f32x16;
typedef __attribute__((ext_vector_type(8))) short short8;
typedef __attribute__((ext_vector_type(8))) unsigned short ushort8;
typedef __attribute__((ext_vector_type(4))) unsigned uint32x4;
typedef unsigned short ushort_t;

__device__ __forceinline__ ushort_t f2bf(float f) {
    union { float f; unsigned u; } v; v.f = f;
    unsigned r = v.u + 0x7FFF + ((v.u >> 16) & 1);   // RNE
    return (ushort_t)(r >> 16);
}

// pack two floats as bf16 pair into one u32 (lo in bits 0..15)
__device__ __forceinline__ unsigned pack2bf(float lo, float hi) {
    return (unsigned)f2bf(lo) | ((unsigned)f2bf(hi) << 16);
}

__device__ __forceinline__ void gload_lds16(const void* g, void* lds_base, unsigned lds_byte_off) {
    auto l = (__attribute__((address_space(3))) unsigned*)((char*)lds_base + lds_byte_off);
    auto p = (const __attribute__((address_space(1))) unsigned*)g;
    __builtin_amdgcn_global_load_lds(p, l, 16, 0, 0);
}

// ---------------- fused fp32 -> bf16 conversion for all 5 inputs -------------
__global__ __launch_bounds__(256) void cvt_all(const float* __restrict__ x,
        const float* __restrict__ Wq, const float* __restrict__ Wk,
        const float* __restrict__ Wv, const float* __restrict__ Wo,
        ushort_t* __restrict__ xb, ushort_t* __restrict__ Wqkv,
        ushort_t* __restrict__ Wob) {
    const int n8x = MM * DD / 8;   // 524288
    const int n8w = DD * DD / 8;   // 131072 = 2^17
    int i = blockIdx.x * 256 + threadIdx.x;
    const float* s;
    ushort_t* d;
    if (i < n8x) {
        s = x + (size_t)i * 8;
        d = xb + (size_t)i * 8;
    } else {
        int j = i - n8x;
        int sel = j >> 17;
        int off = j & (n8w - 1);
        const float* w = sel == 0 ? Wq : sel == 1 ? Wk : sel == 2 ? Wv : Wo;
        s = w + (size_t)off * 8;
        d = (sel < 3 ? Wqkv + (size_t)sel * DD * DD : Wob) + (size_t)off * 8;
    }
    float4 a = *(const float4*)s;
    float4 b = *(const float4*)(s + 4);
    ushort8 o;
    o[0]=f2bf(a.x); o[1]=f2bf(a.y); o[2]=f2bf(a.z); o[3]=f2bf(a.w);
    o[4]=f2bf(b.x); o[5]=f2bf(b.y); o[6]=f2bf(b.z); o[7]=f2bf(b.w);
    *(ushort8*)d = o;
}

// ---------------- GEMM: C[M][N] = A[M][K] * Bw[N][K]^T  (all bf16 in) --------
// 128x128 tile, BK=32, 256 threads = 4 waves (2x2 of 64x64). (round-2 verified)
__global__ __launch_bounds__(256) void gemm128(const ushort_t* __restrict__ A,
                                               const ushort_t* __restrict__ Bw,
                                               ushort_t* __restrict__ Cb,
                                               float* __restrict__ Cf,
                                               const float* __restrict__ bias,
                                               int Mdim, int Ndim, int Kdim) {
    __shared__ ushort_t As[128*32];
    __shared__ ushort_t Bs[128*32];
    const int tid = threadIdx.x;
    const int lane = tid & 63;
    const int wv = tid >> 6;
    const int wr = (wv >> 1) * 64, wc = (wv & 1) * 64;
    const int l16 = lane & 15, kg = lane >> 4;
    const int brow = blockIdx.y * 128;
    const int bcol = blockIdx.x * 128;

    f32x4 acc[4][4];
#pragma unroll
    for (int i = 0; i < 4; i++)
#pragma unroll
        for (int j = 0; j < 4; j++) acc[i][j] = (f32x4){0.f,0.f,0.f,0.f};

    const int c0 = tid, c1 = tid + 256;
    const int ar0 = c0 >> 2, sl0 = (c0 & 3) ^ ((ar0 >> 1) & 3);
    const int ar1 = c1 >> 2, sl1 = (c1 & 3) ^ ((ar1 >> 1) & 3);
    const ushort_t* Ag0 = A + (size_t)(brow + ar0) * Kdim + sl0 * 8;
    const ushort_t* Ag1 = A + (size_t)(brow + ar1) * Kdim + sl1 * 8;
    const ushort_t* Bg0 = Bw + (size_t)(bcol + ar0) * Kdim + sl0 * 8;
    const ushort_t* Bg1 = Bw + (size_t)(bcol + ar1) * Kdim + sl1 * 8;

    for (int k0 = 0; k0 < Kdim; k0 += 32) {
        __syncthreads();
        gload_lds16(Ag0 + k0, As, c0 * 16);
        gload_lds16(Ag1 + k0, As, c1 * 16);
        gload_lds16(Bg0 + k0, Bs, c0 * 16);
        gload_lds16(Bg1 + k0, Bs, c1 * 16);
        __syncthreads();

        short8 af[4], bf[4];
#pragma unroll
        for (int mi = 0; mi < 4; mi++) {
            int row = wr + mi * 16 + l16;
            af[mi] = *(const short8*)((const char*)As + row * 64 + ((kg ^ ((row >> 1) & 3)) * 16));
        }
#pragma unroll
        for (int ni = 0; ni < 4; ni++) {
            int row = wc + ni * 16 + l16;
            bf[ni] = *(const short8*)((const char*)Bs + row * 64 + ((kg ^ ((row >> 1) & 3)) * 16));
        }
#pragma unroll
        for (int mi = 0; mi < 4; mi++)
#pragma unroll
            for (int ni = 0; ni < 4; ni++)
                acc[mi][ni] = __builtin_amdgcn_mfma_f32_16x16x32_bf16(af[mi], bf[ni], acc[mi][ni], 0, 0, 0);
    }

    if (Cb) {
#pragma unroll
        for (int mi = 0; mi < 4; mi++)
#pragma unroll
            for (int ni = 0; ni < 4; ni++) {
                int row = brow + wr + mi * 16 + kg * 4;
                int col = bcol + wc + ni * 16 + l16;
#pragma unroll
                for (int r = 0; r < 4; r++)
                    Cb[(size_t)(row + r) * Ndim + col] = f2bf(acc[mi][ni][r]);
            }
    } else {
#pragma unroll
        for (int mi = 0; mi < 4; mi++)
#pragma unroll
            for (int ni = 0; ni < 4; ni++) {
                int row = brow + wr + mi * 16 + kg * 4;
                int col = bcol + wc + ni * 16 + l16;
                float bv = bias ? bias[col] : 0.f;
#pragma unroll
                for (int r = 0; r < 4; r++)
                    Cf[(size_t)(row + r) * Ndim + col] = acc[mi][ni][r] + bv;
            }
    }
}

// ---------------- V transpose: qkv v-part -> vT[bh][hd][s] -------------------
__global__ __launch_bounds__(256) void transv(const ushort_t* __restrict__ qkv,
                                              ushort_t* __restrict__ vT) {
    int bh = blockIdx.y;
    int b = bh >> 4, h = bh & 15;
    int s0 = blockIdx.x * 64;
    __shared__ ushort_t t[64][72];
    int tid = threadIdx.x;
    int sr = tid >> 2, cb = (tid & 3) * 16;
    const ushort_t* src = qkv + (size_t)(b * SS + s0 + sr) * 3072 + 2048 + h * 64 + cb;
    ushort8 v0 = *(const ushort8*)src;
    ushort8 v1 = *(const ushort8*)(src + 8);
#pragma unroll
    for (int i = 0; i < 8; i++) t[sr][cb + i] = v0[i];
#pragma unroll
    for (int i = 0; i < 8; i++) t[sr][cb + 8 + i] = v1[i];
    __syncthreads();
    int hd = tid >> 2, sb = (tid & 3) * 16;
    ushort_t* dst = vT + ((size_t)bh * 64 + hd) * SS + s0 + sb;
    ushort8 o0, o1;
#pragma unroll
    for (int i = 0; i < 8; i++) o0[i] = t[sb + i][hd];
#pragma unroll
    for (int i = 0; i < 8; i++) o1[i] = t[sb + 8 + i][hd];
    *(ushort8*)dst = o0;
    *(ushort8*)(dst + 8) = o1;
}

// ---------------- attn64: round-2 VERIFIED flash attention (output path) -----
__global__ __launch_bounds__(256) void attn64(const ushort_t* __restrict__ qkv,
                                              const ushort_t* __restrict__ vT,
                                              ushort_t* __restrict__ ctx) {
    int bh = blockIdx.y;
    int b = bh >> 4, h = bh & 15;
    int q0 = blockIdx.x * 64;
    __shared__ ushort_t Ks[64 * 64];
    __shared__ ushort_t Vs[64 * 64];
    __shared__ ushort_t Ps[4][16 * 64];
    int tid = threadIdx.x, lane = tid & 63, wv = tid >> 6;
    int l16 = lane & 15, kg = lane >> 4;

    const ushort_t* qp = qkv + (size_t)(b * SS + q0 + wv * 16 + l16) * 3072 + h * 64 + kg * 8;
    short8 qf0 = *(const short8*)qp;
    short8 qf1 = *(const short8*)(qp + 32);

    const int c0 = tid, c1 = tid + 256;
    const int kr0 = c0 >> 3, sl0 = (c0 & 7) ^ (kr0 & 7);
    const int kr1 = c1 >> 3, sl1 = (c1 & 7) ^ (kr1 & 7);
    const ushort_t* Kg0 = qkv + (size_t)(b * SS + kr0) * 3072 + 1024 + h * 64 + sl0 * 8;
    const ushort_t* Kg1 = qkv + (size_t)(b * SS + kr1) * 3072 + 1024 + h * 64 + sl1 * 8;
    const ushort_t* Vg0 = vT + ((size_t)bh * 64 + kr0) * SS + sl0 * 8;
    const ushort_t* Vg1 = vT + ((size_t)bh * 64 + kr1) * SS + sl1 * 8;

    float mrun[4], lrun[4];
    f32x4 oacc[4];
#pragma unroll
    for (int r = 0; r < 4; r++) { mrun[r] = -1e30f; lrun[r] = 0.f; }
#pragma unroll
    for (int nf = 0; nf < 4; nf++) oacc[nf] = (f32x4){0.f,0.f,0.f,0.f};

    for (int kk = 0; kk < SS; kk += 64) {
        __syncthreads();
        gload_lds16(Kg0 + (size_t)kk * 3072, Ks, c0 * 16);
        gload_lds16(Kg1 + (size_t)kk * 3072, Ks, c1 * 16);
        gload_lds16(Vg0 + kk, Vs, c0 * 16);
        gload_lds16(Vg1 + kk, Vs, c1 * 16);
        __syncthreads();

        f32x4 sa[4];
#pragma unroll
        for (int nf = 0; nf < 4; nf++) {
            sa[nf] = (f32x4){0.f,0.f,0.f,0.f};
            int row = nf * 16 + l16;
            const char* base = (const char*)Ks + row * 128;
            short8 kfa = *(const short8*)(base + ((kg * 16) ^ ((row & 7) << 4)));
            short8 kfb = *(const short8*)(base + ((64 + kg * 16) ^ ((row & 7) << 4)));
            sa[nf] = __builtin_amdgcn_mfma_f32_16x16x32_bf16(qf0, kfa, sa[nf], 0, 0, 0);
            sa[nf] = __builtin_amdgcn_mfma_f32_16x16x32_bf16(qf1, kfb, sa[nf], 0, 0, 0);
        }

        float p[4][4], mnew[4], corr[4];
#pragma unroll
        for (int r = 0; r < 4; r++) {
            float mx = fmaxf(fmaxf(sa[0][r], sa[1][r]), fmaxf(sa[2][r], sa[3][r]));
            mx = fmaxf(mx, __shfl_xor(mx, 1));
            mx = fmaxf(mx, __shfl_xor(mx, 2));
            mx = fmaxf(mx, __shfl_xor(mx, 4));
            mx = fmaxf(mx, __shfl_xor(mx, 8));
            mx *= 0.125f;
            mnew[r] = fmaxf(mrun[r], mx);
            corr[r] = __expf(mrun[r] - mnew[r]);
            mrun[r] = mnew[r];
        }
#pragma unroll
        for (int nf = 0; nf < 4; nf++)
#pragma unroll
            for (int r = 0; r < 4; r++)
                p[nf][r] = __expf(sa[nf][r] * 0.125f - mnew[r]);
#pragma unroll
        for (int r = 0; r < 4; r++) {
            float s = p[0][r] + p[1][r] + p[2][r] + p[3][r];
            s += __shfl_xor(s, 1);
            s += __shfl_xor(s, 2);
            s += __shfl_xor(s, 4);
            s += __shfl_xor(s, 8);
            lrun[r] = lrun[r] * corr[r] + s;
        }
#pragma unroll
        for (int nf = 0; nf < 4; nf++) {
            f32x4 o = oacc[nf];
            o[0] *= corr[0]; o[1] *= corr[1]; o[2] *= corr[2]; o[3] *= corr[3];
            oacc[nf] = o;
        }

        ushort_t* pb = Ps[wv];
#pragma unroll
        for (int r = 0; r < 4; r++) {
            int row = kg * 4 + r;
            char* base = (char*)pb + row * 128;
#pragma unroll
            for (int nf = 0; nf < 4; nf++)
                *(ushort_t*)(base + ((nf * 32 + l16 * 2) ^ ((row & 7) << 4))) = f2bf(p[nf][r]);
        }

#pragma unroll
        for (int ks = 0; ks < 2; ks++) {
            short8 pa = *(const short8*)((const char*)pb + l16 * 128 +
                                         ((ks * 64 + kg * 16) ^ ((l16 & 7) << 4)));
#pragma unroll
            for (int nf = 0; nf < 4; nf++) {
                int vrow = nf * 16 + l16;
                short8 vf = *(const short8*)((const char*)Vs + vrow * 128 +
                                             ((ks * 64 + kg * 16) ^ ((vrow & 7) << 4)));
                oacc[nf] = __builtin_amdgcn_mfma_f32_16x16x32_bf16(pa, vf, oacc[nf], 0, 0, 0);
            }
        }
    }

#pragma unroll
    for (int nf = 0; nf < 4; nf++)
#pragma unroll
        for (int r = 0; r < 4; r++) {
            int row = b * SS + q0 + wv * 16 + kg * 4 + r;
            float val = oacc[nf][r] / lrun[r];
            ctx[(size_t)row * DD + h * 64 + nf * 16 + l16] = f2bf(val);
        }
}

// ---------------- attn128: swapped-operand 32x32 (EXPERIMENTAL, to scratch) --
// Per wave: 32 q-rows (q = lane&31, lane-local through softmax+rescale+epilogue).
// S^T = mfma(K, Q): col=q=lane&31, row=k_local=(reg&3)+8*(reg>>2)+4*hi.
// O^T = mfma(V^T, P^T): col=q, row=hd. P^T B-frags built in-register via
// packed bf16 pairs + half-swap (shfl_xor 32 + select). K/V double-buffered.
__global__ __launch_bounds__(256) void attn128(const ushort_t* __restrict__ qkv,
                                               const ushort_t* __restrict__ vT,
                                               ushort_t* __restrict__ ctx) {
    const int bh = blockIdx.y;
    const int b = bh >> 4, h = bh & 15;
    const int q0 = blockIdx.x * 128;
    __shared__ ushort_t Ks[2][64 * 64];   // [krow][d], 128B rows, XOR-swizzled
    __shared__ ushort_t Vs[2][64 * 64];   // [hd][k],   128B rows, XOR-swizzled
    const int tid = threadIdx.x, lane = tid & 63, wq = tid >> 6;
    const int l31 = lane & 31, hi = lane >> 5;

    const int kr0 = tid >> 3, sl0 = (tid & 7) ^ (kr0 & 7);   // (kr0+32)&7 == kr0&7
    const ushort_t* Kg0 = qkv + (size_t)(b * SS + kr0) * 3072 + 1024 + h * 64 + sl0 * 8;
    const ushort_t* Kg1 = qkv + (size_t)(b * SS + kr0 + 32) * 3072 + 1024 + h * 64 + sl0 * 8;
    const ushort_t* Vg0 = vT + ((size_t)bh * 64 + kr0) * SS + sl0 * 8;
    const ushort_t* Vg1 = vT + ((size_t)bh * 64 + kr0 + 32) * SS + sl0 * 8;
    const unsigned off0 = tid * 16, off1 = (tid + 256) * 16;

    const ushort_t* qp = qkv + (size_t)(b * SS + q0 + wq * 32 + l31) * 3072 + h * 64 + hi * 8;
    short8 qf[4];
#pragma unroll
    for (int m = 0; m < 4; m++) qf[m] = *(const short8*)(qp + m * 16);

    float mrun = -1e30f, lrun = 0.f;
    f32x16 oacc[2];
#pragma unroll
    for (int ht = 0; ht < 2; ht++)
#pragma unroll
        for (int r = 0; r < 16; r++) oacc[ht][r] = 0.f;

    gload_lds16(Kg0, Ks[0], off0);
    gload_lds16(Kg1, Ks[0], off1);
    gload_lds16(Vg0, Vs[0], off0);
    gload_lds16(Vg1, Vs[0], off1);
    __syncthreads();

    for (int t = 0; t < SS / 64; ++t) {
        const int cur = t & 1;
        if (t + 1 < SS / 64) {
            size_t ko = (size_t)(t + 1) * 64 * 3072;
            size_t vo = (size_t)(t + 1) * 64;
            gload_lds16(Kg0 + ko, Ks[cur ^ 1], off0);
            gload_lds16(Kg1 + ko, Ks[cur ^ 1], off1);
            gload_lds16(Vg0 + vo, Vs[cur ^ 1], off0);
            gload_lds16(Vg1 + vo, Vs[cur ^ 1], off1);
        }

        f32x16 sa[2];
#pragma unroll
        for (int kt = 0; kt < 2; kt++) {
#pragma unroll
            for (int r = 0; r < 16; r++) sa[kt][r] = 0.f;
            int row = kt * 32 + l31;
            const char* base = (const char*)Ks[cur] + row * 128;
            int swz = (row & 7) << 4;
#pragma unroll
            for (int m = 0; m < 4; m++) {
                short8 kf = *(const short8*)(base + (((2 * m + hi) << 4) ^ swz));
                sa[kt] = __builtin_amdgcn_mfma_f32_32x32x16_bf16(kf, qf[m], sa[kt], 0, 0, 0);
            }
        }

        float mx = sa[0][0];
#pragma unroll
        for (int kt = 0; kt < 2; kt++)
#pragma unroll
            for (int r = 0; r < 16; r++) mx = fmaxf(mx, sa[kt][r]);
        mx = fmaxf(mx, __shfl_xor(mx, 32));
        float mnew = fmaxf(mrun, mx * 0.125f);
        float corr = __expf(mrun - mnew);
        mrun = mnew;

        float p[2][16];
        float sum = 0.f;
#pragma unroll
        for (int kt = 0; kt < 2; kt++)
#pragma unroll
            for (int r = 0; r < 16; r++) {
                float v = __expf(fmaf(sa[kt][r], 0.125f, -mnew));
                p[kt][r] = v;
                sum += v;
            }
        sum += __shfl_xor(sum, 32);
        lrun = lrun * corr + sum;
#pragma unroll
        for (int ht = 0; ht < 2; ht++)
#pragma unroll
            for (int r = 0; r < 16; r++) oacc[ht][r] *= corr;

        unsigned pk[2][4][2];
#pragma unroll
        for (int kt = 0; kt < 2; kt++)
#pragma unroll
            for (int q2 = 0; q2 < 4; q2++)
#pragma unroll
                for (int i = 0; i < 2; i++)
                    pk[kt][q2][i] = pack2bf(p[kt][q2 * 4 + 2 * i], p[kt][q2 * 4 + 2 * i + 1]);

#pragma unroll
        for (int c = 0; c < 4; c++) {
            const int kt = c >> 1, c2 = c & 1;
            unsigned sa0 = (unsigned)__shfl_xor((int)pk[kt][2 * c2 + 1][0], 32);
            unsigned sa1 = (unsigned)__shfl_xor((int)pk[kt][2 * c2 + 1][1], 32);
            unsigned sb0 = (unsigned)__shfl_xor((int)pk[kt][2 * c2][0], 32);
            unsigned sb1 = (unsigned)__shfl_xor((int)pk[kt][2 * c2][1], 32);
            unsigned b0 = hi ? sa0 : pk[kt][2 * c2][0];
            unsigned b1 = hi ? sa1 : pk[kt][2 * c2][1];
            unsigned b2 = hi ? pk[kt][2 * c2 + 1][0] : sb0;
            unsigned b3 = hi ? pk[kt][2 * c2 + 1][1] : sb1;
            uint32x4 pb = {b0, b1, b2, b3};
            short8 pfrag = __builtin_bit_cast(short8, pb);
#pragma unroll
            for (int ht = 0; ht < 2; ht++) {
                int row = ht * 32 + l31;
                const char* vb = (const char*)Vs[cur] + row * 128;
                short8 vf = *(const short8*)(vb + (((2 * c + hi) << 4) ^ ((row & 7) << 4)));
                oacc[ht] = __builtin_amdgcn_mfma_f32_32x32x16_bf16(vf, pfrag, oacc[ht], 0, 0, 0);
            }
        }
        __syncthreads();
    }

    float inv = 1.f / lrun;
    ushort_t* cbase = ctx + (size_t)(b * SS + q0 + wq * 32 + l31) * DD + h * 64 + hi * 4;
#pragma unroll
    for (int ht = 0; ht < 2; ht++)
#pragma unroll
        for (int q2 = 0; q2 < 4; q2++) {
            uint2 w;
            w.x = pack2bf(oacc[ht][q2 * 4 + 0] * inv, oacc[ht][q2 * 4 + 1] * inv);
            w.y = pack2bf(oacc[ht][q2 * 4 + 2] * inv, oacc[ht][q2 * 4 + 3] * inv);
            *(uint2*)(cbase + ht * 32 + q2 * 8) = w;
        }
}

extern "C" void kernel_launch(void* const* d_in, const int* in_sizes, int n_in,
                              void* d_out, int out_size, void* d_ws, size_t ws_size,
                              hipStream_t stream) {
    const float* x  = (const float*)d_in[0];
    const float* Wq = (const float*)d_in[1];
    const float* Wk = (const float*)d_in[2];
    const float* Wv = (const float*)d_in[3];
    const float* Wo = (const float*)d_in[4];
    const float* bo = (const float*)d_in[5];
    float* out = (float*)d_out;

    char* ws = (char*)d_ws;
    ushort_t* xb   = (ushort_t*)(ws);                       // 8 MB  [4096][1024] (dead after QKV GEMM)
    ushort_t* Wqkv = (ushort_t*)(ws + (8ull  << 20));       // 6 MB  [3072][1024]
    ushort_t* Wob  = (ushort_t*)(ws + (14ull << 20));       // 2 MB  [1024][1024]
    ushort_t* qkv  = (ushort_t*)(ws + (16ull << 20));       // 24 MB [4096][3072]
    ushort_t* vT   = (ushort_t*)(ws + (40ull << 20));       // 8 MB  [32][64][2048]
    ushort_t* ctx  = (ushort_t*)(ws + (48ull << 20));       // 8 MB  [4096][1024]
    ushort_t* ctx2 = xb;                                    // scratch for attn128 probe

    const int n8tot = (MM * DD + 4 * DD * DD) / 8;   // 1048576
    cvt_all<<<n8tot / 256, 256, 0, stream>>>(x, Wq, Wk, Wv, Wo, xb, Wqkv, Wob);

    gemm128<<<dim3(3072 / 128, MM / 128), 256, 0, stream>>>(xb, Wqkv, qkv, nullptr, nullptr,
                                                            MM, 3072, DD);
    transv<<<dim3(SS / 64, BB * HH), 256, 0, stream>>>(qkv, vT);
    // verified path feeds the output
    attn64<<<dim3(SS / 64, BB * HH), 256, 0, stream>>>(qkv, vT, ctx);
    // experimental swapped-operand kernel: timed + profiled, result to scratch
    attn128<<<dim3(SS / 128, BB * HH), 256, 0, stream>>>(qkv, vT, ctx2);
    gemm128<<<dim3(DD / 128, MM / 128), 256, 0, stream>>>(ctx, Wob, nullptr, out, bo,
                                                          MM, DD, DD);
}

// Round 15
// 227.355 us; speedup vs baseline: 1.4716x; 1.4716x over previous
//
#include <hip/hip_runtime.h>
#include <hip/hip_bf16.h>
#include <stdint.h>

#define BB 2
#define SS 2048
#define DD 1024
#define HH 16
#define HDIM 64
#define MM (BB*SS)   // 4096

typedef __attribute__((ext_vector_type(4))) float f32x4;
typedef __attribute__((ext_vector_type(16))) float f32x16;
typedef __attribute__((ext_vector_type(8))) short short8;
typedef __attribute__((ext_vector_type(8))) unsigned short ushort8;
typedef __attribute__((ext_vector_type(4))) unsigned uint32x4;
typedef unsigned short ushort_t;

__device__ __forceinline__ ushort_t f2bf(float f) {
    union { float f; unsigned u; } v; v.f = f;
    unsigned r = v.u + 0x7FFF + ((v.u >> 16) & 1);   // RNE
    return (ushort_t)(r >> 16);
}

// pack two floats as bf16 pair into one u32 (lo in bits 0..15)
__device__ __forceinline__ unsigned pack2bf(float lo, float hi) {
    return (unsigned)f2bf(lo) | ((unsigned)f2bf(hi) << 16);
}

__device__ __forceinline__ void gload_lds16(const void* g, void* lds_base, unsigned lds_byte_off) {
    auto l = (__attribute__((address_space(3))) unsigned*)((char*)lds_base + lds_byte_off);
    auto p = (const __attribute__((address_space(1))) unsigned*)g;
    __builtin_amdgcn_global_load_lds(p, l, 16, 0, 0);
}

// ---------------- fused fp32 -> bf16 conversion for all 5 inputs -------------
__global__ __launch_bounds__(256) void cvt_all(const float* __restrict__ x,
        const float* __restrict__ Wq, const float* __restrict__ Wk,
        const float* __restrict__ Wv, const float* __restrict__ Wo,
        ushort_t* __restrict__ xb, ushort_t* __restrict__ Wqkv,
        ushort_t* __restrict__ Wob) {
    const int n8x = MM * DD / 8;   // 524288
    const int n8w = DD * DD / 8;   // 131072 = 2^17
    int i = blockIdx.x * 256 + threadIdx.x;
    const float* s;
    ushort_t* d;
    if (i < n8x) {
        s = x + (size_t)i * 8;
        d = xb + (size_t)i * 8;
    } else {
        int j = i - n8x;
        int sel = j >> 17;
        int off = j & (n8w - 1);
        const float* w = sel == 0 ? Wq : sel == 1 ? Wk : sel == 2 ? Wv : Wo;
        s = w + (size_t)off * 8;
        d = (sel < 3 ? Wqkv + (size_t)sel * DD * DD : Wob) + (size_t)off * 8;
    }
    float4 a = *(const float4*)s;
    float4 b = *(const float4*)(s + 4);
    ushort8 o;
    o[0]=f2bf(a.x); o[1]=f2bf(a.y); o[2]=f2bf(a.z); o[3]=f2bf(a.w);
    o[4]=f2bf(b.x); o[5]=f2bf(b.y); o[6]=f2bf(b.z); o[7]=f2bf(b.w);
    *(ushort8*)d = o;
}

// ---------------- GEMM: C[M][N] = A[M][K] * Bw[N][K]^T  (all bf16 in) --------
// 128x128 tile, BK=32, 256 threads = 4 waves (2x2 of 64x64). (round-2 verified)
__global__ __launch_bounds__(256) void gemm128(const ushort_t* __restrict__ A,
                                               const ushort_t* __restrict__ Bw,
                                               ushort_t* __restrict__ Cb,
                                               float* __restrict__ Cf,
                                               const float* __restrict__ bias,
                                               int Mdim, int Ndim, int Kdim) {
    __shared__ ushort_t As[128*32];
    __shared__ ushort_t Bs[128*32];
    const int tid = threadIdx.x;
    const int lane = tid & 63;
    const int wv = tid >> 6;
    const int wr = (wv >> 1) * 64, wc = (wv & 1) * 64;
    const int l16 = lane & 15, kg = lane >> 4;
    const int brow = blockIdx.y * 128;
    const int bcol = blockIdx.x * 128;

    f32x4 acc[4][4];
#pragma unroll
    for (int i = 0; i < 4; i++)
#pragma unroll
        for (int j = 0; j < 4; j++) acc[i][j] = (f32x4){0.f,0.f,0.f,0.f};

    const int c0 = tid, c1 = tid + 256;
    const int ar0 = c0 >> 2, sl0 = (c0 & 3) ^ ((ar0 >> 1) & 3);
    const int ar1 = c1 >> 2, sl1 = (c1 & 3) ^ ((ar1 >> 1) & 3);
    const ushort_t* Ag0 = A + (size_t)(brow + ar0) * Kdim + sl0 * 8;
    const ushort_t* Ag1 = A + (size_t)(brow + ar1) * Kdim + sl1 * 8;
    const ushort_t* Bg0 = Bw + (size_t)(bcol + ar0) * Kdim + sl0 * 8;
    const ushort_t* Bg1 = Bw + (size_t)(bcol + ar1) * Kdim + sl1 * 8;

    for (int k0 = 0; k0 < Kdim; k0 += 32) {
        __syncthreads();
        gload_lds16(Ag0 + k0, As, c0 * 16);
        gload_lds16(Ag1 + k0, As, c1 * 16);
        gload_lds16(Bg0 + k0, Bs, c0 * 16);
        gload_lds16(Bg1 + k0, Bs, c1 * 16);
        __syncthreads();

        short8 af[4], bf[4];
#pragma unroll
        for (int mi = 0; mi < 4; mi++) {
            int row = wr + mi * 16 + l16;
            af[mi] = *(const short8*)((const char*)As + row * 64 + ((kg ^ ((row >> 1) & 3)) * 16));
        }
#pragma unroll
        for (int ni = 0; ni < 4; ni++) {
            int row = wc + ni * 16 + l16;
            bf[ni] = *(const short8*)((const char*)Bs + row * 64 + ((kg ^ ((row >> 1) & 3)) * 16));
        }
#pragma unroll
        for (int mi = 0; mi < 4; mi++)
#pragma unroll
            for (int ni = 0; ni < 4; ni++)
                acc[mi][ni] = __builtin_amdgcn_mfma_f32_16x16x32_bf16(af[mi], bf[ni], acc[mi][ni], 0, 0, 0);
    }

    if (Cb) {
#pragma unroll
        for (int mi = 0; mi < 4; mi++)
#pragma unroll
            for (int ni = 0; ni < 4; ni++) {
                int row = brow + wr + mi * 16 + kg * 4;
                int col = bcol + wc + ni * 16 + l16;
#pragma unroll
                for (int r = 0; r < 4; r++)
                    Cb[(size_t)(row + r) * Ndim + col] = f2bf(acc[mi][ni][r]);
            }
    } else {
#pragma unroll
        for (int mi = 0; mi < 4; mi++)
#pragma unroll
            for (int ni = 0; ni < 4; ni++) {
                int row = brow + wr + mi * 16 + kg * 4;
                int col = bcol + wc + ni * 16 + l16;
                float bv = bias ? bias[col] : 0.f;
#pragma unroll
                for (int r = 0; r < 4; r++)
                    Cf[(size_t)(row + r) * Ndim + col] = acc[mi][ni][r] + bv;
            }
    }
}

// ---------------- V transpose: qkv v-part -> vT[bh][hd][s] -------------------
__global__ __launch_bounds__(256) void transv(const ushort_t* __restrict__ qkv,
                                              ushort_t* __restrict__ vT) {
    int bh = blockIdx.y;
    int b = bh >> 4, h = bh & 15;
    int s0 = blockIdx.x * 64;
    __shared__ ushort_t t[64][72];
    int tid = threadIdx.x;
    int sr = tid >> 2, cb = (tid & 3) * 16;
    const ushort_t* src = qkv + (size_t)(b * SS + s0 + sr) * 3072 + 2048 + h * 64 + cb;
    ushort8 v0 = *(const ushort8*)src;
    ushort8 v1 = *(const ushort8*)(src + 8);
#pragma unroll
    for (int i = 0; i < 8; i++) t[sr][cb + i] = v0[i];
#pragma unroll
    for (int i = 0; i < 8; i++) t[sr][cb + 8 + i] = v1[i];
    __syncthreads();
    int hd = tid >> 2, sb = (tid & 3) * 16;
    ushort_t* dst = vT + ((size_t)bh * 64 + hd) * SS + s0 + sb;
    ushort8 o0, o1;
#pragma unroll
    for (int i = 0; i < 8; i++) o0[i] = t[sb + i][hd];
#pragma unroll
    for (int i = 0; i < 8; i++) o1[i] = t[sb + 8 + i][hd];
    *(ushort8*)dst = o0;
    *(ushort8*)(dst + 8) = o1;
}

// ---------------- flash attention, swapped-operand 32x32 structure -----------
// Measured round 8: ~64 us (2.0x over the 16x16 attn64). Now the output path.
// Per wave: 32 q-rows (q = lane&31, lane-local through softmax+rescale+epilogue).
// S^T = mfma(K, Q): col=q=lane&31, row=k_local=(reg&3)+8*(reg>>2)+4*hi.
// O^T = mfma(V^T, P^T): col=q, row=hd. P^T B-frags built in-register via
// packed bf16 pairs + half-swap (shfl_xor 32 + select). K/V double-buffered.
__global__ __launch_bounds__(256) void attn128(const ushort_t* __restrict__ qkv,
                                               const ushort_t* __restrict__ vT,
                                               ushort_t* __restrict__ ctx) {
    const int bh = blockIdx.y;
    const int b = bh >> 4, h = bh & 15;
    const int q0 = blockIdx.x * 128;
    __shared__ ushort_t Ks[2][64 * 64];   // [krow][d], 128B rows, XOR-swizzled
    __shared__ ushort_t Vs[2][64 * 64];   // [hd][k],   128B rows, XOR-swizzled
    const int tid = threadIdx.x, lane = tid & 63, wq = tid >> 6;
    const int l31 = lane & 31, hi = lane >> 5;

    const int kr0 = tid >> 3, sl0 = (tid & 7) ^ (kr0 & 7);   // (kr0+32)&7 == kr0&7
    const ushort_t* Kg0 = qkv + (size_t)(b * SS + kr0) * 3072 + 1024 + h * 64 + sl0 * 8;
    const ushort_t* Kg1 = qkv + (size_t)(b * SS + kr0 + 32) * 3072 + 1024 + h * 64 + sl0 * 8;
    const ushort_t* Vg0 = vT + ((size_t)bh * 64 + kr0) * SS + sl0 * 8;
    const ushort_t* Vg1 = vT + ((size_t)bh * 64 + kr0 + 32) * SS + sl0 * 8;
    const unsigned off0 = tid * 16, off1 = (tid + 256) * 16;

    const ushort_t* qp = qkv + (size_t)(b * SS + q0 + wq * 32 + l31) * 3072 + h * 64 + hi * 8;
    short8 qf[4];
#pragma unroll
    for (int m = 0; m < 4; m++) qf[m] = *(const short8*)(qp + m * 16);

    float mrun = -1e30f, lrun = 0.f;
    f32x16 oacc[2];
#pragma unroll
    for (int ht = 0; ht < 2; ht++)
#pragma unroll
        for (int r = 0; r < 16; r++) oacc[ht][r] = 0.f;

    gload_lds16(Kg0, Ks[0], off0);
    gload_lds16(Kg1, Ks[0], off1);
    gload_lds16(Vg0, Vs[0], off0);
    gload_lds16(Vg1, Vs[0], off1);
    __syncthreads();

    for (int t = 0; t < SS / 64; ++t) {
        const int cur = t & 1;
        if (t + 1 < SS / 64) {
            size_t ko = (size_t)(t + 1) * 64 * 3072;
            size_t vo = (size_t)(t + 1) * 64;
            gload_lds16(Kg0 + ko, Ks[cur ^ 1], off0);
            gload_lds16(Kg1 + ko, Ks[cur ^ 1], off1);
            gload_lds16(Vg0 + vo, Vs[cur ^ 1], off0);
            gload_lds16(Vg1 + vo, Vs[cur ^ 1], off1);
        }

        f32x16 sa[2];
#pragma unroll
        for (int kt = 0; kt < 2; kt++) {
#pragma unroll
            for (int r = 0; r < 16; r++) sa[kt][r] = 0.f;
            int row = kt * 32 + l31;
            const char* base = (const char*)Ks[cur] + row * 128;
            int swz = (row & 7) << 4;
#pragma unroll
            for (int m = 0; m < 4; m++) {
                short8 kf = *(const short8*)(base + (((2 * m + hi) << 4) ^ swz));
                sa[kt] = __builtin_amdgcn_mfma_f32_32x32x16_bf16(kf, qf[m], sa[kt], 0, 0, 0);
            }
        }

        float mx = sa[0][0];
#pragma unroll
        for (int kt = 0; kt < 2; kt++)
#pragma unroll
            for (int r = 0; r < 16; r++) mx = fmaxf(mx, sa[kt][r]);
        mx = fmaxf(mx, __shfl_xor(mx, 32));
        float mnew = fmaxf(mrun, mx * 0.125f);
        float corr = __expf(mrun - mnew);
        mrun = mnew;

        float p[2][16];
        float sum = 0.f;
#pragma unroll
        for (int kt = 0; kt < 2; kt++)
#pragma unroll
            for (int r = 0; r < 16; r++) {
                float v = __expf(fmaf(sa[kt][r], 0.125f, -mnew));
                p[kt][r] = v;
                sum += v;
            }
        sum += __shfl_xor(sum, 32);
        lrun = lrun * corr + sum;
#pragma unroll
        for (int ht = 0; ht < 2; ht++)
#pragma unroll
            for (int r = 0; r < 16; r++) oacc[ht][r] *= corr;

        unsigned pk[2][4][2];
#pragma unroll
        for (int kt = 0; kt < 2; kt++)
#pragma unroll
            for (int q2 = 0; q2 < 4; q2++)
#pragma unroll
                for (int i = 0; i < 2; i++)
                    pk[kt][q2][i] = pack2bf(p[kt][q2 * 4 + 2 * i], p[kt][q2 * 4 + 2 * i + 1]);

#pragma unroll
        for (int c = 0; c < 4; c++) {
            const int kt = c >> 1, c2 = c & 1;
            unsigned sa0 = (unsigned)__shfl_xor((int)pk[kt][2 * c2 + 1][0], 32);
            unsigned sa1 = (unsigned)__shfl_xor((int)pk[kt][2 * c2 + 1][1], 32);
            unsigned sb0 = (unsigned)__shfl_xor((int)pk[kt][2 * c2][0], 32);
            unsigned sb1 = (unsigned)__shfl_xor((int)pk[kt][2 * c2][1], 32);
            unsigned b0 = hi ? sa0 : pk[kt][2 * c2][0];
            unsigned b1 = hi ? sa1 : pk[kt][2 * c2][1];
            unsigned b2 = hi ? pk[kt][2 * c2 + 1][0] : sb0;
            unsigned b3 = hi ? pk[kt][2 * c2 + 1][1] : sb1;
            uint32x4 pb = {b0, b1, b2, b3};
            short8 pfrag = __builtin_bit_cast(short8, pb);
#pragma unroll
            for (int ht = 0; ht < 2; ht++) {
                int row = ht * 32 + l31;
                const char* vb = (const char*)Vs[cur] + row * 128;
                short8 vf = *(const short8*)(vb + (((2 * c + hi) << 4) ^ ((row & 7) << 4)));
                oacc[ht] = __builtin_amdgcn_mfma_f32_32x32x16_bf16(vf, pfrag, oacc[ht], 0, 0, 0);
            }
        }
        __syncthreads();
    }

    float inv = 1.f / lrun;
    ushort_t* cbase = ctx + (size_t)(b * SS + q0 + wq * 32 + l31) * DD + h * 64 + hi * 4;
#pragma unroll
    for (int ht = 0; ht < 2; ht++)
#pragma unroll
        for (int q2 = 0; q2 < 4; q2++) {
            uint2 w;
            w.x = pack2bf(oacc[ht][q2 * 4 + 0] * inv, oacc[ht][q2 * 4 + 1] * inv);
            w.y = pack2bf(oacc[ht][q2 * 4 + 2] * inv, oacc[ht][q2 * 4 + 3] * inv);
            *(uint2*)(cbase + ht * 32 + q2 * 8) = w;
        }
}

extern "C" void kernel_launch(void* const* d_in, const int* in_sizes, int n_in,
                              void* d_out, int out_size, void* d_ws, size_t ws_size,
                              hipStream_t stream) {
    const float* x  = (const float*)d_in[0];
    const float* Wq = (const float*)d_in[1];
    const float* Wk = (const float*)d_in[2];
    const float* Wv = (const float*)d_in[3];
    const float* Wo = (const float*)d_in[4];
    const float* bo = (const float*)d_in[5];
    float* out = (float*)d_out;

    char* ws = (char*)d_ws;
    ushort_t* xb   = (ushort_t*)(ws);                       // 8 MB  [4096][1024]
    ushort_t* Wqkv = (ushort_t*)(ws + (8ull  << 20));       // 6 MB  [3072][1024]
    ushort_t* Wob  = (ushort_t*)(ws + (14ull << 20));       // 2 MB  [1024][1024]
    ushort_t* qkv  = (ushort_t*)(ws + (16ull << 20));       // 24 MB [4096][3072]
    ushort_t* vT   = (ushort_t*)(ws + (40ull << 20));       // 8 MB  [32][64][2048]
    ushort_t* ctx  = (ushort_t*)(ws + (48ull << 20));       // 8 MB  [4096][1024]

    const int n8tot = (MM * DD + 4 * DD * DD) / 8;   // 1048576
    cvt_all<<<n8tot / 256, 256, 0, stream>>>(x, Wq, Wk, Wv, Wo, xb, Wqkv, Wob);

    gemm128<<<dim3(3072 / 128, MM / 128), 256, 0, stream>>>(xb, Wqkv, qkv, nullptr, nullptr,
                                                            MM, 3072, DD);
    transv<<<dim3(SS / 64, BB * HH), 256, 0, stream>>>(qkv, vT);
    attn128<<<dim3(SS / 128, BB * HH), 256, 0, stream>>>(qkv, vT, ctx);
    gemm128<<<dim3(DD / 128, MM / 128), 256, 0, stream>>>(ctx, Wob, nullptr, out, bo,
                                                          MM, DD, DD);
}